// Round 1
// baseline (14886.359 us; speedup 1.0000x reference)
//
#include <hip/hip_runtime.h>
#include <hip/hip_bf16.h>

// ---------------------------------------------------------------------------
// AttentionHeteroConv: h = x@Wnb^T+b; scatter {max,min,sum,mean} over edges;
// tokens=[self,max,min,sum,mean]; 4-head MHA over S=5; out = self + mean_s(attn)
// ---------------------------------------------------------------------------

#define C 128
#define NHEAD 4
#define DH 32

// order-preserving float<->uint encoding for atomic max/min
__device__ __forceinline__ unsigned enc_ord(float f) {
    unsigned u = __float_as_uint(f);
    return (u & 0x80000000u) ? ~u : (u | 0x80000000u);
}
__device__ __forceinline__ float dec_ord(unsigned k) {
    unsigned u = (k & 0x80000000u) ? (k ^ 0x80000000u) : ~k;
    return __uint_as_float(u);
}
#define ENC_NEGINF 0x007FFFFFu   // enc(-inf)
#define ENC_POSINF 0xFF800000u   // enc(+inf)

// ---------------------------------------------------------------------------
// K1: init aggregation buffers (ws is poisoned 0xAA before every launch)
// ---------------------------------------------------------------------------
__global__ __launch_bounds__(256) void init_kernel(
    float* __restrict__ sum_all, unsigned* __restrict__ mx_all,
    unsigned* __restrict__ mn_all, float* __restrict__ cnt_all,
    int tot4, int tot_nodes)
{
    int i = blockIdx.x * 256 + threadIdx.x;
    if (i < tot4) {
        ((float4*)sum_all)[i] = make_float4(0.f, 0.f, 0.f, 0.f);
        ((uint4*)mx_all)[i] = make_uint4(ENC_NEGINF, ENC_NEGINF, ENC_NEGINF, ENC_NEGINF);
        ((uint4*)mn_all)[i] = make_uint4(ENC_POSINF, ENC_POSINF, ENC_POSINF, ENC_POSINF);
    }
    if (i < tot_nodes) cnt_all[i] = 0.f;
}

// ---------------------------------------------------------------------------
// K2: transform: h = x@Wnb^T + bnb ; self = x@Wself^T + bself
// block = 256 threads: tid<128 -> Wnb cols, tid>=128 -> Wself cols.
// 32-row A tile in LDS.
// ---------------------------------------------------------------------------
__global__ __launch_bounds__(256) void transform_kernel(
    const float* __restrict__ x, int n_rows,
    const float* __restrict__ Wnb, const float* __restrict__ bnb,
    const float* __restrict__ Wself, const float* __restrict__ bself,
    float* __restrict__ h, float* __restrict__ selfout)
{
    __shared__ float At[32][C];
    const int tid = threadIdx.x;
    const int row0 = blockIdx.x * 32;

    // cooperative coalesced load of 32x128 tile (as float4)
    for (int i = tid; i < 32 * 32; i += 256) {
        int r = i >> 5, c4 = i & 31;
        float4 v = make_float4(0.f, 0.f, 0.f, 0.f);
        if (row0 + r < n_rows) v = ((const float4*)x)[(size_t)(row0 + r) * 32 + c4];
        ((float4*)At[r])[c4] = v;
    }
    __syncthreads();

    const int col = tid & 127;
    const float* W = (tid < 128) ? Wnb : Wself;
    const float* bb = (tid < 128) ? bnb : bself;
    float* outp = (tid < 128) ? h : selfout;

    float acc[32];
#pragma unroll
    for (int r = 0; r < 32; r++) acc[r] = 0.f;

    const float4* w4 = (const float4*)(W + (size_t)col * C);
    for (int k4 = 0; k4 < 32; k4 += 4) {
        float4 w0 = w4[k4], w1 = w4[k4 + 1], w2 = w4[k4 + 2], w3 = w4[k4 + 3];
#pragma unroll
        for (int r = 0; r < 32; r++) {
            const float4* a4 = (const float4*)At[r];
            float4 a0 = a4[k4], a1 = a4[k4 + 1], a2 = a4[k4 + 2], a3 = a4[k4 + 3];
            acc[r] += a0.x * w0.x + a0.y * w0.y + a0.z * w0.z + a0.w * w0.w
                    + a1.x * w1.x + a1.y * w1.y + a1.z * w1.z + a1.w * w1.w
                    + a2.x * w2.x + a2.y * w2.y + a2.z * w2.z + a2.w * w2.w
                    + a3.x * w3.x + a3.y * w3.y + a3.z * w3.z + a3.w * w3.w;
        }
    }
    const float bias = bb[col];
#pragma unroll
    for (int r = 0; r < 32; r++) {
        int row = row0 + r;
        if (row < n_rows) outp[(size_t)row * C + col] = acc[r] + bias;
    }
}

// ---------------------------------------------------------------------------
// K3: edge aggregation. One wave (64 lanes) per edge, 2 channels/lane.
// ---------------------------------------------------------------------------
__global__ __launch_bounds__(256) void aggregate_kernel(
    const float* __restrict__ h_src, const int* __restrict__ src,
    const int* __restrict__ dst, int n_edges,
    float* __restrict__ sumb, unsigned* __restrict__ mxb,
    unsigned* __restrict__ mnb, float* __restrict__ cntb)
{
    int e = blockIdx.x * 4 + (threadIdx.x >> 6);
    if (e >= n_edges) return;
    int lane = threadIdx.x & 63;
    int s = src[e], d = dst[e];
    float2 v = ((const float2*)(h_src + (size_t)s * C))[lane];
    size_t base = (size_t)d * C + lane * 2;
    atomicAdd(sumb + base, v.x);
    atomicAdd(sumb + base + 1, v.y);
    atomicMax(mxb + base, enc_ord(v.x));
    atomicMax(mxb + base + 1, enc_ord(v.y));
    atomicMin(mnb + base, enc_ord(v.x));
    atomicMin(mnb + base + 1, enc_ord(v.y));
    if (lane == 0) atomicAdd(cntb + d, 1.f);
}

// ---------------------------------------------------------------------------
// K4: per-node 5-token MHA. NT=8 nodes per block of 256 threads.
// io holds self_feat on entry, final output on exit (in place, block-local).
// Simplifications: out_proj applied to mean_s(o_s); o-mean accumulated via
// column-summed attention weights.
// ---------------------------------------------------------------------------
#define NT 8
__global__ __launch_bounds__(256) void attn_kernel(
    const float* __restrict__ sum, const unsigned* __restrict__ mxe,
    const unsigned* __restrict__ mne, const float* __restrict__ cnt,
    const float* __restrict__ Wip, const float* __restrict__ bip,
    const float* __restrict__ Wop, const float* __restrict__ bop,
    float* __restrict__ io, int n_nodes)
{
    __shared__ float tok[5 * NT][C];      // 20 KB  (row = nl*5 + s)
    __shared__ float qkvh[5 * NT][96];    // 15 KB  (q:0-31, k:32-63, v:64-95)
    __shared__ float att[NT][5][5];       // 0.8 KB
    __shared__ float omean[NT][C];        // 4 KB

    const int tid = threadIdx.x;
    const int node0 = blockIdx.x * NT;

    // build 5 tokens per node + zero omean
    for (int i = tid; i < NT * C; i += 256) {
        int nl = i >> 7, c = i & 127;
        int node = node0 + nl;
        float sf = 0.f, sm = 0.f, mxv = 0.f, mnv = 0.f, ct = 0.f;
        if (node < n_nodes) {
            sf = io[(size_t)node * C + c];
            sm = sum[(size_t)node * C + c];
            ct = cnt[node];
            if (ct > 0.f) {
                mxv = dec_ord(mxe[(size_t)node * C + c]);
                mnv = dec_ord(mne[(size_t)node * C + c]);
            }
        }
        float mean = sm * (1.f / fmaxf(ct, 1.f));
        tok[nl * 5 + 0][c] = sf;
        tok[nl * 5 + 1][c] = mxv;
        tok[nl * 5 + 2][c] = mnv;
        tok[nl * 5 + 3][c] = sm;
        tok[nl * 5 + 4][c] = mean;
        omean[nl][c] = 0.f;
    }
    __syncthreads();

    const float scale = 0.17677669529663687f; // 1/sqrt(32)

    for (int h = 0; h < NHEAD; h++) {
        // qkv projection for this head: [40 rows] x [96 cols]
        for (int d = tid; d < 5 * NT * 96; d += 256) {
            int row = d / 96, colh = d - row * 96;
            int part = colh >> 5, dh = colh & 31;
            int wrow = part * C + h * DH + dh;
            const float4* w4 = (const float4*)(Wip + (size_t)wrow * C);
            const float4* a4 = (const float4*)(tok[row]);
            float acc = 0.f;
#pragma unroll 8
            for (int c4 = 0; c4 < 32; c4++) {
                float4 a = a4[c4]; float4 w = w4[c4];
                acc += a.x * w.x + a.y * w.y + a.z * w.z + a.w * w.w;
            }
            acc += bip[wrow];
            if (part == 0) acc *= scale;
            qkvh[row][colh] = acc;
        }
        __syncthreads();

        // scores + softmax: one thread per (node, query-token i)
        if (tid < NT * 5) {
            int nl = tid / 5, i = tid - nl * 5;
            float sc[5];
            float m = -3.4e38f;
#pragma unroll
            for (int j = 0; j < 5; j++) {
                float s = 0.f;
#pragma unroll
                for (int d2 = 0; d2 < DH; d2++)
                    s += qkvh[nl * 5 + i][d2] * qkvh[nl * 5 + j][DH + d2];
                sc[j] = s; m = fmaxf(m, s);
            }
            float l = 0.f;
#pragma unroll
            for (int j = 0; j < 5; j++) { sc[j] = __expf(sc[j] - m); l += sc[j]; }
            float inv = 0.2f / l;   // 1/5 for the S-mean folded in
#pragma unroll
            for (int j = 0; j < 5; j++) att[nl][i][j] = sc[j] * inv;
        }
        __syncthreads();

        // o-mean accumulate: thread per (node, dh): NT*32 == 256
        {
            int nl = tid >> 5, d2 = tid & 31;
            float wj[5];
#pragma unroll
            for (int j = 0; j < 5; j++)
                wj[j] = att[nl][0][j] + att[nl][1][j] + att[nl][2][j]
                      + att[nl][3][j] + att[nl][4][j];
            float acc = 0.f;
#pragma unroll
            for (int j = 0; j < 5; j++) acc += wj[j] * qkvh[nl * 5 + j][2 * DH + d2];
            omean[nl][h * DH + d2] += acc;
        }
        __syncthreads();
    }

    // out_proj on omean + residual self
    for (int d = tid; d < NT * C; d += 256) {
        int nl = d >> 7, c = d & 127;
        const float4* w4 = (const float4*)(Wop + (size_t)c * C);
        const float4* a4 = (const float4*)(omean[nl]);
        float acc = 0.f;
#pragma unroll 8
        for (int c4 = 0; c4 < 32; c4++) {
            float4 a = a4[c4]; float4 w = w4[c4];
            acc += a.x * w.x + a.y * w.y + a.z * w.z + a.w * w.w;
        }
        int node = node0 + nl;
        if (node < n_nodes)
            io[(size_t)node * C + c] = tok[nl * 5 + 0][c] + acc + bop[c];
    }
}

// ---------------------------------------------------------------------------
extern "C" void kernel_launch(void* const* d_in, const int* in_sizes, int n_in,
                              void* d_out, int out_size, void* d_ws, size_t ws_size,
                              hipStream_t stream) {
    const float* x_user = (const float*)d_in[0];
    const float* x_item = (const float*)d_in[1];
    const int*   ei_u2i = (const int*)d_in[2];
    const int*   ei_i2u = (const int*)d_in[3];
    const float* W_nb   = (const float*)d_in[4];
    const float* b_nb   = (const float*)d_in[5];
    const float* W_self = (const float*)d_in[6];
    const float* b_self = (const float*)d_in[7];
    const float* Wip    = (const float*)d_in[8];
    const float* bip    = (const float*)d_in[9];
    const float* Wop    = (const float*)d_in[10];
    const float* bop    = (const float*)d_in[11];

    const int NU = in_sizes[0] / C;
    const int NI = in_sizes[1] / C;
    const int E1 = in_sizes[2] / 2;
    const int E2 = in_sizes[3] / 2;

    float* out_user = (float*)d_out;
    float* out_item = out_user + (size_t)NU * C;

    // workspace layout
    float* ws = (float*)d_ws;
    const size_t rc = (size_t)(NU + NI) * C;
    float*    h_all   = ws;                            // (NU+NI)*128
    float*    sum_all = h_all + rc;                    // (NU+NI)*128
    unsigned* mx_all  = (unsigned*)(sum_all + rc);     // (NU+NI)*128
    unsigned* mn_all  = mx_all + rc;                   // (NU+NI)*128
    float*    cnt_all = (float*)(mn_all + rc);         // NU+NI

    float*    h_user = h_all;
    float*    h_item = h_all + (size_t)NU * C;
    float*    sum_user = sum_all;
    float*    sum_item = sum_all + (size_t)NU * C;
    unsigned* mx_user = mx_all;
    unsigned* mx_item = mx_all + (size_t)NU * C;
    unsigned* mn_user = mn_all;
    unsigned* mn_item = mn_all + (size_t)NU * C;
    float*    cnt_user = cnt_all;
    float*    cnt_item = cnt_all + NU;

    // K1: init aggregation buffers
    const int tot4 = (int)(rc / 4);
    init_kernel<<<(tot4 + 255) / 256, 256, 0, stream>>>(
        sum_all, mx_all, mn_all, cnt_all, tot4, NU + NI);

    // K2: transforms (self feat goes straight into d_out)
    transform_kernel<<<(NU + 31) / 32, 256, 0, stream>>>(
        x_user, NU, W_nb, b_nb, W_self, b_self, h_user, out_user);
    transform_kernel<<<(NI + 31) / 32, 256, 0, stream>>>(
        x_item, NI, W_nb, b_nb, W_self, b_self, h_item, out_item);

    // K3: aggregations (u2i -> item buffers, i2u -> user buffers)
    aggregate_kernel<<<(E1 + 3) / 4, 256, 0, stream>>>(
        h_user, ei_u2i, ei_u2i + E1, E1, sum_item, mx_item, mn_item, cnt_item);
    aggregate_kernel<<<(E2 + 3) / 4, 256, 0, stream>>>(
        h_item, ei_i2u, ei_i2u + E2, E2, sum_user, mx_user, mn_user, cnt_user);

    // K4: per-node attention, in place on d_out
    attn_kernel<<<(NU + NT - 1) / NT, 256, 0, stream>>>(
        sum_user, mx_user, mn_user, cnt_user, Wip, bip, Wop, bop, out_user, NU);
    attn_kernel<<<(NI + NT - 1) / NT, 256, 0, stream>>>(
        sum_item, mx_item, mn_item, cnt_item, Wip, bip, Wop, bop, out_item, NI);
}

// Round 2
// 4685.865 us; speedup vs baseline: 3.1769x; 3.1769x over previous
//
#include <hip/hip_runtime.h>
#include <hip/hip_bf16.h>

// ---------------------------------------------------------------------------
// AttentionHeteroConv: h = x@Wnb^T+b; scatter {max,min,sum,mean} over edges;
// tokens=[self,max,min,sum,mean]; 4-head MHA over S=5; out = self + mean_s(attn)
//
// R2: attention path rewritten as register-tiled GEMM (qkv) + fused softmax/PV
//     + separate out_proj GEMM. mean-token qkv derived algebraically.
// ---------------------------------------------------------------------------

#define C 128
#define NHEAD 4
#define DH 32
#define QK_SCALE 0.17677669529663687f  // 1/sqrt(32)

// order-preserving float<->uint encoding for atomic max/min
__device__ __forceinline__ unsigned enc_ord(float f) {
    unsigned u = __float_as_uint(f);
    return (u & 0x80000000u) ? ~u : (u | 0x80000000u);
}
__device__ __forceinline__ float dec_ord(unsigned k) {
    unsigned u = (k & 0x80000000u) ? (k ^ 0x80000000u) : ~k;
    return __uint_as_float(u);
}
#define ENC_NEGINF 0x007FFFFFu   // enc(-inf)
#define ENC_POSINF 0xFF800000u   // enc(+inf)

// ---------------------------------------------------------------------------
// K1: init aggregation buffers (ws is poisoned 0xAA before every launch)
// ---------------------------------------------------------------------------
__global__ __launch_bounds__(256) void init_kernel(
    float* __restrict__ sum_all, unsigned* __restrict__ mx_all,
    unsigned* __restrict__ mn_all, float* __restrict__ cnt_all,
    int tot4, int tot_nodes)
{
    int i = blockIdx.x * 256 + threadIdx.x;
    if (i < tot4) {
        ((float4*)sum_all)[i] = make_float4(0.f, 0.f, 0.f, 0.f);
        ((uint4*)mx_all)[i] = make_uint4(ENC_NEGINF, ENC_NEGINF, ENC_NEGINF, ENC_NEGINF);
        ((uint4*)mn_all)[i] = make_uint4(ENC_POSINF, ENC_POSINF, ENC_POSINF, ENC_POSINF);
    }
    if (i < tot_nodes) cnt_all[i] = 0.f;
}

// ---------------------------------------------------------------------------
// K2: transform: h = x@Wnb^T + bnb ; self = x@Wself^T + bself
// ---------------------------------------------------------------------------
__global__ __launch_bounds__(256) void transform_kernel(
    const float* __restrict__ x, int n_rows,
    const float* __restrict__ Wnb, const float* __restrict__ bnb,
    const float* __restrict__ Wself, const float* __restrict__ bself,
    float* __restrict__ h, float* __restrict__ selfout)
{
    __shared__ float At[32][C];
    const int tid = threadIdx.x;
    const int row0 = blockIdx.x * 32;

    for (int i = tid; i < 32 * 32; i += 256) {
        int r = i >> 5, c4 = i & 31;
        float4 v = make_float4(0.f, 0.f, 0.f, 0.f);
        if (row0 + r < n_rows) v = ((const float4*)x)[(size_t)(row0 + r) * 32 + c4];
        ((float4*)At[r])[c4] = v;
    }
    __syncthreads();

    const int col = tid & 127;
    const float* W = (tid < 128) ? Wnb : Wself;
    const float* bb = (tid < 128) ? bnb : bself;
    float* outp = (tid < 128) ? h : selfout;

    float acc[32];
#pragma unroll
    for (int r = 0; r < 32; r++) acc[r] = 0.f;

    const float4* w4 = (const float4*)(W + (size_t)col * C);
    for (int k4 = 0; k4 < 32; k4 += 4) {
        float4 w0 = w4[k4], w1 = w4[k4 + 1], w2 = w4[k4 + 2], w3 = w4[k4 + 3];
#pragma unroll
        for (int r = 0; r < 32; r++) {
            const float4* a4 = (const float4*)At[r];
            float4 a0 = a4[k4], a1 = a4[k4 + 1], a2 = a4[k4 + 2], a3 = a4[k4 + 3];
            acc[r] += a0.x * w0.x + a0.y * w0.y + a0.z * w0.z + a0.w * w0.w
                    + a1.x * w1.x + a1.y * w1.y + a1.z * w1.z + a1.w * w1.w
                    + a2.x * w2.x + a2.y * w2.y + a2.z * w2.z + a2.w * w2.w
                    + a3.x * w3.x + a3.y * w3.y + a3.z * w3.z + a3.w * w3.w;
        }
    }
    const float bias = bb[col];
#pragma unroll
    for (int r = 0; r < 32; r++) {
        int row = row0 + r;
        if (row < n_rows) outp[(size_t)row * C + col] = acc[r] + bias;
    }
}

// ---------------------------------------------------------------------------
// K3: edge aggregation. One wave (64 lanes) per edge, 2 channels/lane.
// ---------------------------------------------------------------------------
__global__ __launch_bounds__(256) void aggregate_kernel(
    const float* __restrict__ h_src, const int* __restrict__ src,
    const int* __restrict__ dst, int n_edges,
    float* __restrict__ sumb, unsigned* __restrict__ mxb,
    unsigned* __restrict__ mnb, float* __restrict__ cntb)
{
    int e = blockIdx.x * 4 + (threadIdx.x >> 6);
    if (e >= n_edges) return;
    int lane = threadIdx.x & 63;
    int s = src[e], d = dst[e];
    float2 v = ((const float2*)(h_src + (size_t)s * C))[lane];
    size_t base = (size_t)d * C + lane * 2;
    atomicAdd(sumb + base, v.x);
    atomicAdd(sumb + base + 1, v.y);
    atomicMax(mxb + base, enc_ord(v.x));
    atomicMax(mxb + base + 1, enc_ord(v.y));
    atomicMin(mnb + base, enc_ord(v.x));
    atomicMin(mnb + base + 1, enc_ord(v.y));
    if (lane == 0) atomicAdd(cntb + d, 1.f);
}

// ---------------------------------------------------------------------------
// K4: fused qkv-GEMM + attention for 8 nodes/block.
// Virtual A rows (4/node: self,max,min,sum) -> qkv GEMM (32x384, K=128) with
// 4Mx12N register micro-tiles; C-tile overlaid into LDS; mean-row derived as
// (qkv_sum - b)/cnt + b; per-head 5x5 softmax + PV; omean -> global.
// LDS region layout (floats):
//   GEMM phase:  As[32][132] @0 (m-major, pad132), Bs[32][388] @4224 (k-major)
//   attn phase:  qkv[40][384] @0   (rows: node*5 + s, s=0..4)
// ---------------------------------------------------------------------------
#define ATN 8           // nodes per block
#define RSZ 16896       // region floats (As 4224 + Bs 12416 = 16640 <= 16896)
#define BS_OFF 4224

__global__ __launch_bounds__(256, 2) void attn_fused_kernel(
    const float* __restrict__ sum, const unsigned* __restrict__ mxe,
    const unsigned* __restrict__ mne, const float* __restrict__ cnt,
    const float* __restrict__ selfF,
    const float* __restrict__ Wip, const float* __restrict__ bip,
    float* __restrict__ omean_g, int n_nodes)
{
    __shared__ float R[RSZ];
    __shared__ float omean[ATN][C];
    __shared__ float att[ATN][5][5];
    __shared__ float bipS[384];
    __shared__ float cinv[ATN];

    const int tid = threadIdx.x;
    const int node0 = blockIdx.x * ATN;

    // ---- P0: stage bip, cnt-inverse, and virtual-token A tile ----
    for (int i = tid; i < 384; i += 256) bipS[i] = bip[i];
    if (tid < ATN) {
        int node = node0 + tid;
        float ct = (node < n_nodes) ? cnt[node] : 0.f;
        cinv[tid] = 1.f / fmaxf(ct, 1.f);
    }
#pragma unroll
    for (int i = 0; i < 4; i++) {
        int id = tid + i * 256;          // 1024 float4 = 32 rows x 32
        int r = id >> 5, c4 = id & 31;
        int node = node0 + (r >> 2), s = r & 3;
        float4 v = make_float4(0.f, 0.f, 0.f, 0.f);
        if (node < n_nodes) {
            size_t off = (size_t)node * 32 + c4;
            if (s == 0)      v = ((const float4*)selfF)[off];
            else if (s == 3) v = ((const float4*)sum)[off];
            else {
                float ct = cnt[node];
                if (ct > 0.f) {
                    uint4 u = (s == 1) ? ((const uint4*)mxe)[off]
                                       : ((const uint4*)mne)[off];
                    v = make_float4(dec_ord(u.x), dec_ord(u.y),
                                    dec_ord(u.z), dec_ord(u.w));
                }
            }
        }
        *(float4*)&R[r * 132 + c4 * 4] = v;
    }

    // ---- P1: GEMM qkv = A @ Wip^T  (M=32, N=384, K=128) ----
    const int tn = tid & 31;        // 32 n-groups of 12 cols
    const int tm = tid >> 5;        // 8 m-groups of 4 rows
    float acc[4][12];
#pragma unroll
    for (int m = 0; m < 4; m++)
#pragma unroll
        for (int n = 0; n < 12; n++) acc[m][n] = 0.f;

    for (int ks = 0; ks < 4; ks++) {
        __syncthreads();
        // stage Bs[kk][n] = Wip[n][ks*32+kk], pad-388 rows
        for (int i = 0; i < 12; i++) {
            int id = tid + i * 256;          // 3072 = 384 n x 8 q
            int n = id >> 3, q = id & 7;
            float4 w = ((const float4*)Wip)[(size_t)n * 32 + ks * 8 + q];
            R[BS_OFF + (q * 4 + 0) * 388 + n] = w.x;
            R[BS_OFF + (q * 4 + 1) * 388 + n] = w.y;
            R[BS_OFF + (q * 4 + 2) * 388 + n] = w.z;
            R[BS_OFF + (q * 4 + 3) * 388 + n] = w.w;
        }
        __syncthreads();
#pragma unroll 2
        for (int k4 = 0; k4 < 8; k4++) {
            float4 a[4];
#pragma unroll
            for (int m = 0; m < 4; m++)
                a[m] = *(const float4*)&R[(tm * 4 + m) * 132 + ks * 32 + k4 * 4];
#pragma unroll
            for (int kk = 0; kk < 4; kk++) {
                const float* bp = &R[BS_OFF + (k4 * 4 + kk) * 388 + tn * 12];
                float4 b0 = *(const float4*)(bp);
                float4 b1 = *(const float4*)(bp + 4);
                float4 b2 = *(const float4*)(bp + 8);
#pragma unroll
                for (int m = 0; m < 4; m++) {
                    float av = ((const float*)&a[m])[kk];
                    acc[m][0] += av * b0.x;  acc[m][1] += av * b0.y;
                    acc[m][2] += av * b0.z;  acc[m][3] += av * b0.w;
                    acc[m][4] += av * b1.x;  acc[m][5] += av * b1.y;
                    acc[m][6] += av * b1.z;  acc[m][7] += av * b1.w;
                    acc[m][8] += av * b2.x;  acc[m][9] += av * b2.y;
                    acc[m][10] += av * b2.z; acc[m][11] += av * b2.w;
                }
            }
        }
    }

    // ---- P2: C-tile (+bias) -> qkv LDS overlay, rows node*5+s ----
    __syncthreads();
#pragma unroll
    for (int m = 0; m < 4; m++) {
        int mr = tm * 4 + m;
        int node = mr >> 2, s = mr & 3;
        float* q = &R[(node * 5 + s) * 384 + tn * 12];
#pragma unroll
        for (int n = 0; n < 12; n++) q[n] = acc[m][n] + bipS[tn * 12 + n];
    }
    __syncthreads();

    // ---- P3: derive mean rows: (qkv_sum - b)/cnt + b ----
    for (int i = 0; i < 12; i++) {
        int id = tid + i * 256;              // 3072 = 8 x 384
        int n = id / 384, c = id - n * 384;
        float b = bipS[c];
        R[(n * 5 + 4) * 384 + c] = (R[(n * 5 + 3) * 384 + c] - b) * cinv[n] + b;
    }
    __syncthreads();

    // ---- P4: per-head scores/softmax/PV ----
    for (int h = 0; h < NHEAD; h++) {
        if (tid < ATN * 25) {
            int n = tid / 25, ij = tid - n * 25, i = ij / 5, j = ij - (ij / 5) * 5;
            const float* qr = &R[(n * 5 + i) * 384 + h * DH];
            const float* kr = &R[(n * 5 + j) * 384 + C + h * DH];
            float s = 0.f;
#pragma unroll
            for (int d = 0; d < DH; d++) s += qr[d] * kr[d];
            att[n][i][j] = s * QK_SCALE;
        }
        __syncthreads();
        if (tid < ATN * 5) {
            int n = tid / 5, i = tid - n * 5;
            float m = att[n][i][0];
#pragma unroll
            for (int j = 1; j < 5; j++) m = fmaxf(m, att[n][i][j]);
            float e[5], l = 0.f;
#pragma unroll
            for (int j = 0; j < 5; j++) { e[j] = __expf(att[n][i][j] - m); l += e[j]; }
            float inv = 0.2f / l;            // fold 1/5 S-mean
#pragma unroll
            for (int j = 0; j < 5; j++) att[n][i][j] = e[j] * inv;
        }
        __syncthreads();
        {
            int n = tid >> 5, d = tid & 31;  // 8 x 32 = 256
            float a2 = 0.f;
#pragma unroll
            for (int j = 0; j < 5; j++) {
                float wj = att[n][0][j] + att[n][1][j] + att[n][2][j]
                         + att[n][3][j] + att[n][4][j];
                a2 += wj * R[(n * 5 + j) * 384 + 2 * C + h * DH + d];
            }
            omean[n][h * DH + d] = a2;
        }
        __syncthreads();
    }

    // ---- P5: omean -> global ----
#pragma unroll
    for (int i = 0; i < 4; i++) {
        int id = tid + i * 256;              // 1024 = 8 x 128
        int n = id >> 7, c = id & 127;
        int node = node0 + n;
        if (node < n_nodes) omean_g[(size_t)node * C + c] = omean[n][c];
    }
}

// ---------------------------------------------------------------------------
// K5: out = self(d_out) + omean @ Wop^T + bop.  Tile 32M x 128N, K=128.
// ---------------------------------------------------------------------------
__global__ __launch_bounds__(256, 4) void outproj_kernel(
    const float* __restrict__ omean_g, const float* __restrict__ Wop,
    const float* __restrict__ bop, float* __restrict__ out, int M)
{
    __shared__ float As[32 * 132];
    __shared__ float Bs[32 * 132];
    __shared__ float bopS[C];
    const int tid = threadIdx.x;
    const int m0 = blockIdx.x * 32;

    if (tid < C) bopS[tid] = bop[tid];
#pragma unroll
    for (int i = 0; i < 4; i++) {
        int id = tid + i * 256;
        int r = id >> 5, c4 = id & 31;
        float4 v = make_float4(0.f, 0.f, 0.f, 0.f);
        int m = m0 + r;
        if (m < M) v = ((const float4*)omean_g)[(size_t)m * 32 + c4];
        *(float4*)&As[r * 132 + c4 * 4] = v;
    }

    const int tn = tid & 31;    // 32 n-groups x 4 cols
    const int tm = tid >> 5;    // 8 m-groups x 4 rows
    float acc[4][4];
#pragma unroll
    for (int m = 0; m < 4; m++)
#pragma unroll
        for (int n = 0; n < 4; n++) acc[m][n] = 0.f;

    for (int ks = 0; ks < 4; ks++) {
        __syncthreads();
        for (int i = 0; i < 4; i++) {
            int id = tid + i * 256;          // 1024 = 128 n x 8 q
            int n = id >> 3, q = id & 7;
            float4 w = ((const float4*)Wop)[(size_t)n * 32 + ks * 8 + q];
            Bs[(q * 4 + 0) * 132 + n] = w.x;
            Bs[(q * 4 + 1) * 132 + n] = w.y;
            Bs[(q * 4 + 2) * 132 + n] = w.z;
            Bs[(q * 4 + 3) * 132 + n] = w.w;
        }
        __syncthreads();
#pragma unroll 4
        for (int k4 = 0; k4 < 8; k4++) {
            float4 a[4];
#pragma unroll
            for (int m = 0; m < 4; m++)
                a[m] = *(const float4*)&As[(tm * 4 + m) * 132 + ks * 32 + k4 * 4];
#pragma unroll
            for (int kk = 0; kk < 4; kk++) {
                float4 b = *(const float4*)&Bs[(k4 * 4 + kk) * 132 + tn * 4];
#pragma unroll
                for (int m = 0; m < 4; m++) {
                    float av = ((const float*)&a[m])[kk];
                    acc[m][0] += av * b.x; acc[m][1] += av * b.y;
                    acc[m][2] += av * b.z; acc[m][3] += av * b.w;
                }
            }
        }
    }

#pragma unroll
    for (int m = 0; m < 4; m++) {
        int row = m0 + tm * 4 + m;
        if (row < M) {
            float4* o = (float4*)&out[(size_t)row * C + tn * 4];
            float4 r = *o;                   // residual self_feat
            r.x += acc[m][0] + bopS[tn * 4 + 0];
            r.y += acc[m][1] + bopS[tn * 4 + 1];
            r.z += acc[m][2] + bopS[tn * 4 + 2];
            r.w += acc[m][3] + bopS[tn * 4 + 3];
            *o = r;
        }
    }
}

// ---------------------------------------------------------------------------
extern "C" void kernel_launch(void* const* d_in, const int* in_sizes, int n_in,
                              void* d_out, int out_size, void* d_ws, size_t ws_size,
                              hipStream_t stream) {
    const float* x_user = (const float*)d_in[0];
    const float* x_item = (const float*)d_in[1];
    const int*   ei_u2i = (const int*)d_in[2];
    const int*   ei_i2u = (const int*)d_in[3];
    const float* W_nb   = (const float*)d_in[4];
    const float* b_nb   = (const float*)d_in[5];
    const float* W_self = (const float*)d_in[6];
    const float* b_self = (const float*)d_in[7];
    const float* Wip    = (const float*)d_in[8];
    const float* bip    = (const float*)d_in[9];
    const float* Wop    = (const float*)d_in[10];
    const float* bop    = (const float*)d_in[11];

    const int NU = in_sizes[0] / C;
    const int NI = in_sizes[1] / C;
    const int E1 = in_sizes[2] / 2;
    const int E2 = in_sizes[3] / 2;

    float* out_user = (float*)d_out;
    float* out_item = out_user + (size_t)NU * C;

    // workspace layout (same footprint as R1; h buffer reused as omean later)
    float* ws = (float*)d_ws;
    const size_t rc = (size_t)(NU + NI) * C;
    float*    h_all   = ws;                            // (NU+NI)*128, later omean
    float*    sum_all = h_all + rc;
    unsigned* mx_all  = (unsigned*)(sum_all + rc);
    unsigned* mn_all  = mx_all + rc;
    float*    cnt_all = (float*)(mn_all + rc);

    float*    h_user = h_all;
    float*    h_item = h_all + (size_t)NU * C;
    float*    sum_user = sum_all;
    float*    sum_item = sum_all + (size_t)NU * C;
    unsigned* mx_user = mx_all;
    unsigned* mx_item = mx_all + (size_t)NU * C;
    unsigned* mn_user = mn_all;
    unsigned* mn_item = mn_all + (size_t)NU * C;
    float*    cnt_user = cnt_all;
    float*    cnt_item = cnt_all + NU;

    const int tot4 = (int)(rc / 4);
    init_kernel<<<(tot4 + 255) / 256, 256, 0, stream>>>(
        sum_all, mx_all, mn_all, cnt_all, tot4, NU + NI);

    transform_kernel<<<(NU + 31) / 32, 256, 0, stream>>>(
        x_user, NU, W_nb, b_nb, W_self, b_self, h_user, out_user);
    transform_kernel<<<(NI + 31) / 32, 256, 0, stream>>>(
        x_item, NI, W_nb, b_nb, W_self, b_self, h_item, out_item);

    aggregate_kernel<<<(E1 + 3) / 4, 256, 0, stream>>>(
        h_user, ei_u2i, ei_u2i + E1, E1, sum_item, mx_item, mn_item, cnt_item);
    aggregate_kernel<<<(E2 + 3) / 4, 256, 0, stream>>>(
        h_item, ei_i2u, ei_i2u + E2, E2, sum_user, mx_user, mn_user, cnt_user);

    // fused qkv-GEMM + attention; omean overlays the (now dead) h buffer
    attn_fused_kernel<<<(NU + ATN - 1) / ATN, 256, 0, stream>>>(
        sum_user, mx_user, mn_user, cnt_user, out_user, Wip, bip, h_user, NU);
    attn_fused_kernel<<<(NI + ATN - 1) / ATN, 256, 0, stream>>>(
        sum_item, mx_item, mn_item, cnt_item, out_item, Wip, bip, h_item, NI);

    // out = self + omean @ Wop^T + bop (user and item in one launch)
    outproj_kernel<<<(NU + NI + 31) / 32, 256, 0, stream>>>(
        h_all, Wop, bop, (float*)d_out, NU + NI);
}

// Round 3
// 1530.855 us; speedup vs baseline: 9.7242x; 3.0609x over previous
//
#include <hip/hip_runtime.h>
#include <hip/hip_bf16.h>

// ---------------------------------------------------------------------------
// AttentionHeteroConv: h = x@Wnb^T+b; gather {max,min,sum} per dst via CSR;
// tokens=[self,max,min,sum,mean]; 4-head MHA over S=5; out = self + mean_s(attn)
//
// R3: scatter->gather. CSR built on device (hist + wave-scan + fill); the
//     gather-aggregate is fused into the attention kernel (sum/max/min land
//     directly in the GEMM A-tile in LDS). No atomic float RMW, no init pass,
//     no sum/mx/mn global buffers.
// ---------------------------------------------------------------------------

#define C 128
#define NHEAD 4
#define DH 32
#define QK_SCALE 0.17677669529663687f  // 1/sqrt(32)

// ---------------------------------------------------------------------------
// K2: transform: h = x@Wnb^T + bnb ; self = x@Wself^T + bself
// ---------------------------------------------------------------------------
__global__ __launch_bounds__(256) void transform_kernel(
    const float* __restrict__ x, int n_rows,
    const float* __restrict__ Wnb, const float* __restrict__ bnb,
    const float* __restrict__ Wself, const float* __restrict__ bself,
    float* __restrict__ h, float* __restrict__ selfout)
{
    __shared__ float At[32][C];
    const int tid = threadIdx.x;
    const int row0 = blockIdx.x * 32;

    for (int i = tid; i < 32 * 32; i += 256) {
        int r = i >> 5, c4 = i & 31;
        float4 v = make_float4(0.f, 0.f, 0.f, 0.f);
        if (row0 + r < n_rows) v = ((const float4*)x)[(size_t)(row0 + r) * 32 + c4];
        ((float4*)At[r])[c4] = v;
    }
    __syncthreads();

    const int col = tid & 127;
    const float* W = (tid < 128) ? Wnb : Wself;
    const float* bb = (tid < 128) ? bnb : bself;
    float* outp = (tid < 128) ? h : selfout;

    float acc[32];
#pragma unroll
    for (int r = 0; r < 32; r++) acc[r] = 0.f;

    const float4* w4 = (const float4*)(W + (size_t)col * C);
    for (int k4 = 0; k4 < 32; k4 += 4) {
        float4 w0 = w4[k4], w1 = w4[k4 + 1], w2 = w4[k4 + 2], w3 = w4[k4 + 3];
#pragma unroll
        for (int r = 0; r < 32; r++) {
            const float4* a4 = (const float4*)At[r];
            float4 a0 = a4[k4], a1 = a4[k4 + 1], a2 = a4[k4 + 2], a3 = a4[k4 + 3];
            acc[r] += a0.x * w0.x + a0.y * w0.y + a0.z * w0.z + a0.w * w0.w
                    + a1.x * w1.x + a1.y * w1.y + a1.z * w1.z + a1.w * w1.w
                    + a2.x * w2.x + a2.y * w2.y + a2.z * w2.z + a2.w * w2.w
                    + a3.x * w3.x + a3.y * w3.y + a3.z * w3.z + a3.w * w3.w;
        }
    }
    const float bias = bb[col];
#pragma unroll
    for (int r = 0; r < 32; r++) {
        int row = row0 + r;
        if (row < n_rows) outp[(size_t)row * C + col] = acc[r] + bias;
    }
}

// ---------------------------------------------------------------------------
// CSR build: zero + histogram + exclusive-scan (single block) + fill.
// After fill, cur[n] = end offset of node n (start = cur[n-1], cur[-1]=0).
// ---------------------------------------------------------------------------
__global__ __launch_bounds__(256) void zero_kernel(int* __restrict__ p, int n)
{
    int i = blockIdx.x * 256 + threadIdx.x;
    if (i < n) p[i] = 0;
}

__global__ __launch_bounds__(256) void hist_kernel(
    const int* __restrict__ dst, int n, int* __restrict__ cur)
{
    int i = blockIdx.x * 256 + threadIdx.x;
    if (i < n) atomicAdd(&cur[dst[i]], 1);
}

__global__ __launch_bounds__(1024) void scan_kernel(int* __restrict__ cur, int n)
{
    __shared__ int wsum[16];
    __shared__ int carryS;
    const int tid = threadIdx.x, lane = tid & 63, wv = tid >> 6;
    if (tid == 0) carryS = 0;
    __syncthreads();
    for (int base = 0; base < n; base += 1024) {
        int i = base + tid;
        int v = (i < n) ? cur[i] : 0;
        int x = v;
#pragma unroll
        for (int d = 1; d < 64; d <<= 1) {
            int t = __shfl_up(x, d, 64);
            if (lane >= d) x += t;
        }
        if (lane == 63) wsum[wv] = x;
        int carry = carryS;            // last written before trailing barrier
        __syncthreads();
        int wpre = 0;
#pragma unroll
        for (int w2 = 0; w2 < 16; w2++) wpre += (w2 < wv) ? wsum[w2] : 0;
        int excl = x - v + wpre + carry;
        if (i < n) cur[i] = excl;
        __syncthreads();
        if (tid == 0) {
            int t = 0;
#pragma unroll
            for (int w2 = 0; w2 < 16; w2++) t += wsum[w2];
            carryS = carry + t;
        }
        __syncthreads();
    }
}

__global__ __launch_bounds__(256) void fill_kernel(
    const int* __restrict__ src, const int* __restrict__ dst, int n,
    int* __restrict__ cur, int* __restrict__ csr)
{
    int i = blockIdx.x * 256 + threadIdx.x;
    if (i < n) {
        int p = atomicAdd(&cur[dst[i]], 1);
        csr[p] = src[i];
    }
}

// ---------------------------------------------------------------------------
// K4: fused gather-aggregate + qkv-GEMM + attention for 8 nodes/block.
// A rows (4/node: self,max,min,sum) built in LDS: self from global, max/min/
// sum gathered from h_src via CSR. qkv GEMM (32x384, K=128), 4Mx12N register
// micro-tiles; C-tile overlaid into LDS; mean row = (qkv_sum - b)*cinv + b;
// per-head 5x5 softmax + PV; omean -> global.
// LDS region R (floats):
//   GEMM phase:  As[32][132] @0 (m-major), Bs[32][388] @4224 (k-major)
//   attn phase:  qkv[40][384] @0  (rows: node*5 + s)
// ---------------------------------------------------------------------------
#define ATN 8           // nodes per block
#define RSZ 16896
#define BS_OFF 4224

__global__ __launch_bounds__(256, 2) void attn_fused_kernel(
    const float* __restrict__ h_src, const int* __restrict__ csr,
    const int* __restrict__ cur, const float* __restrict__ selfF,
    const float* __restrict__ Wip, const float* __restrict__ bip,
    float* __restrict__ omean_g, int n_nodes)
{
    __shared__ float R[RSZ];
    __shared__ float omean[ATN][C];
    __shared__ float att[ATN][5][5];
    __shared__ float bipS[384];
    __shared__ float cinv[ATN];

    const int tid = threadIdx.x;
    const int lane = tid & 63;
    const int wv = tid >> 6;
    const int node0 = blockIdx.x * ATN;

    // ---- P0a: stage bip + self rows ----
    for (int i = tid; i < 384; i += 256) bipS[i] = bip[i];
    {
        int r = tid >> 5, c4 = tid & 31;     // 8 rows x 32 float4
        int node = node0 + r;
        float4 v = make_float4(0.f, 0.f, 0.f, 0.f);
        if (node < n_nodes) v = ((const float4*)selfF)[(size_t)node * 32 + c4];
        *(float4*)&R[(r * 4 + 0) * 132 + c4 * 4] = v;
    }

    // ---- P0b: gather-aggregate max/min/sum (2 nodes per wave) ----
    const float2* h2 = (const float2*)h_src;
#pragma unroll
    for (int half = 0; half < 2; half++) {
        int nl = wv * 2 + half;
        int node = node0 + nl;
        float2 vs = make_float2(0.f, 0.f);
        float2 vmx = make_float2(-3.4e38f, -3.4e38f);
        float2 vmn = make_float2(3.4e38f, 3.4e38f);
        int deg = 0;
        if (node < n_nodes) {
            int start = (node == 0) ? 0 : cur[node - 1];
            int end = cur[node];
            deg = end - start;
            int e = start;
            for (; e + 4 <= end; e += 4) {
                int s0 = csr[e], s1 = csr[e + 1], s2 = csr[e + 2], s3 = csr[e + 3];
                float2 v0 = h2[(size_t)s0 * 64 + lane];
                float2 v1 = h2[(size_t)s1 * 64 + lane];
                float2 v2 = h2[(size_t)s2 * 64 + lane];
                float2 v3 = h2[(size_t)s3 * 64 + lane];
                vs.x += v0.x + v1.x + v2.x + v3.x;
                vs.y += v0.y + v1.y + v2.y + v3.y;
                vmx.x = fmaxf(fmaxf(vmx.x, v0.x), fmaxf(v1.x, fmaxf(v2.x, v3.x)));
                vmx.y = fmaxf(fmaxf(vmx.y, v0.y), fmaxf(v1.y, fmaxf(v2.y, v3.y)));
                vmn.x = fminf(fminf(vmn.x, v0.x), fminf(v1.x, fminf(v2.x, v3.x)));
                vmn.y = fminf(fminf(vmn.y, v0.y), fminf(v1.y, fminf(v2.y, v3.y)));
            }
            for (; e < end; e++) {
                int s0 = csr[e];
                float2 v0 = h2[(size_t)s0 * 64 + lane];
                vs.x += v0.x; vs.y += v0.y;
                vmx.x = fmaxf(vmx.x, v0.x); vmx.y = fmaxf(vmx.y, v0.y);
                vmn.x = fminf(vmn.x, v0.x); vmn.y = fminf(vmn.y, v0.y);
            }
        }
        if (deg == 0) {
            vmx = make_float2(0.f, 0.f);
            vmn = make_float2(0.f, 0.f);
        }
        *(float2*)&R[(nl * 4 + 1) * 132 + 2 * lane] = vmx;
        *(float2*)&R[(nl * 4 + 2) * 132 + 2 * lane] = vmn;
        *(float2*)&R[(nl * 4 + 3) * 132 + 2 * lane] = vs;
        if (lane == 0) cinv[nl] = 1.f / (float)max(deg, 1);
    }

    // ---- P1: GEMM qkv = A @ Wip^T  (M=32, N=384, K=128) ----
    const int tn = tid & 31;        // 32 n-groups of 12 cols
    const int tm = tid >> 5;        // 8 m-groups of 4 rows
    float acc[4][12];
#pragma unroll
    for (int m = 0; m < 4; m++)
#pragma unroll
        for (int n = 0; n < 12; n++) acc[m][n] = 0.f;

    for (int ks = 0; ks < 4; ks++) {
        __syncthreads();
        for (int i = 0; i < 12; i++) {
            int id = tid + i * 256;          // 3072 = 384 n x 8 q
            int n = id >> 3, q = id & 7;
            float4 w = ((const float4*)Wip)[(size_t)n * 32 + ks * 8 + q];
            R[BS_OFF + (q * 4 + 0) * 388 + n] = w.x;
            R[BS_OFF + (q * 4 + 1) * 388 + n] = w.y;
            R[BS_OFF + (q * 4 + 2) * 388 + n] = w.z;
            R[BS_OFF + (q * 4 + 3) * 388 + n] = w.w;
        }
        __syncthreads();
#pragma unroll 2
        for (int k4 = 0; k4 < 8; k4++) {
            float4 a[4];
#pragma unroll
            for (int m = 0; m < 4; m++)
                a[m] = *(const float4*)&R[(tm * 4 + m) * 132 + ks * 32 + k4 * 4];
#pragma unroll
            for (int kk = 0; kk < 4; kk++) {
                const float* bp = &R[BS_OFF + (k4 * 4 + kk) * 388 + tn * 12];
                float4 b0 = *(const float4*)(bp);
                float4 b1 = *(const float4*)(bp + 4);
                float4 b2 = *(const float4*)(bp + 8);
#pragma unroll
                for (int m = 0; m < 4; m++) {
                    float av = ((const float*)&a[m])[kk];
                    acc[m][0] += av * b0.x;  acc[m][1] += av * b0.y;
                    acc[m][2] += av * b0.z;  acc[m][3] += av * b0.w;
                    acc[m][4] += av * b1.x;  acc[m][5] += av * b1.y;
                    acc[m][6] += av * b1.z;  acc[m][7] += av * b1.w;
                    acc[m][8] += av * b2.x;  acc[m][9] += av * b2.y;
                    acc[m][10] += av * b2.z; acc[m][11] += av * b2.w;
                }
            }
        }
    }

    // ---- P2: C-tile (+bias) -> qkv LDS overlay, rows node*5+s ----
    __syncthreads();
#pragma unroll
    for (int m = 0; m < 4; m++) {
        int mr = tm * 4 + m;
        int node = mr >> 2, s = mr & 3;
        float* q = &R[(node * 5 + s) * 384 + tn * 12];
#pragma unroll
        for (int n = 0; n < 12; n++) q[n] = acc[m][n] + bipS[tn * 12 + n];
    }
    __syncthreads();

    // ---- P3: derive mean rows: (qkv_sum - b)*cinv + b ----
    for (int i = 0; i < 12; i++) {
        int id = tid + i * 256;              // 3072 = 8 x 384
        int n = id / 384, c = id - n * 384;
        float b = bipS[c];
        R[(n * 5 + 4) * 384 + c] = (R[(n * 5 + 3) * 384 + c] - b) * cinv[n] + b;
    }
    __syncthreads();

    // ---- P4: per-head scores/softmax/PV ----
    for (int h = 0; h < NHEAD; h++) {
        if (tid < ATN * 25) {
            int n = tid / 25, ij = tid - n * 25, i = ij / 5, j = ij - (ij / 5) * 5;
            const float* qr = &R[(n * 5 + i) * 384 + h * DH];
            const float* kr = &R[(n * 5 + j) * 384 + C + h * DH];
            float s = 0.f;
#pragma unroll
            for (int d = 0; d < DH; d++) s += qr[d] * kr[d];
            att[n][i][j] = s * QK_SCALE;
        }
        __syncthreads();
        if (tid < ATN * 5) {
            int n = tid / 5, i = tid - n * 5;
            float m = att[n][i][0];
#pragma unroll
            for (int j = 1; j < 5; j++) m = fmaxf(m, att[n][i][j]);
            float e[5], l = 0.f;
#pragma unroll
            for (int j = 0; j < 5; j++) { e[j] = __expf(att[n][i][j] - m); l += e[j]; }
            float inv = 0.2f / l;            // fold 1/5 S-mean
#pragma unroll
            for (int j = 0; j < 5; j++) att[n][i][j] = e[j] * inv;
        }
        __syncthreads();
        {
            int n = tid >> 5, d = tid & 31;  // 8 x 32 = 256
            float a2 = 0.f;
#pragma unroll
            for (int j = 0; j < 5; j++) {
                float wj = att[n][0][j] + att[n][1][j] + att[n][2][j]
                         + att[n][3][j] + att[n][4][j];
                a2 += wj * R[(n * 5 + j) * 384 + 2 * C + h * DH + d];
            }
            omean[n][h * DH + d] = a2;
        }
        __syncthreads();
    }

    // ---- P5: omean -> global ----
#pragma unroll
    for (int i = 0; i < 4; i++) {
        int id = tid + i * 256;              // 1024 = 8 x 128
        int n = id >> 7, c = id & 127;
        int node = node0 + n;
        if (node < n_nodes) omean_g[(size_t)node * C + c] = omean[n][c];
    }
}

// ---------------------------------------------------------------------------
// K5: out = self(d_out) + omean @ Wop^T + bop.  Tile 32M x 128N, K=128.
// ---------------------------------------------------------------------------
__global__ __launch_bounds__(256, 4) void outproj_kernel(
    const float* __restrict__ omean_g, const float* __restrict__ Wop,
    const float* __restrict__ bop, float* __restrict__ out, int M)
{
    __shared__ float As[32 * 132];
    __shared__ float Bs[32 * 132];
    __shared__ float bopS[C];
    const int tid = threadIdx.x;
    const int m0 = blockIdx.x * 32;

    if (tid < C) bopS[tid] = bop[tid];
#pragma unroll
    for (int i = 0; i < 4; i++) {
        int id = tid + i * 256;
        int r = id >> 5, c4 = id & 31;
        float4 v = make_float4(0.f, 0.f, 0.f, 0.f);
        int m = m0 + r;
        if (m < M) v = ((const float4*)omean_g)[(size_t)m * 32 + c4];
        *(float4*)&As[r * 132 + c4 * 4] = v;
    }

    const int tn = tid & 31;
    const int tm = tid >> 5;
    float acc[4][4];
#pragma unroll
    for (int m = 0; m < 4; m++)
#pragma unroll
        for (int n = 0; n < 4; n++) acc[m][n] = 0.f;

    for (int ks = 0; ks < 4; ks++) {
        __syncthreads();
        for (int i = 0; i < 4; i++) {
            int id = tid + i * 256;          // 1024 = 128 n x 8 q
            int n = id >> 3, q = id & 7;
            float4 w = ((const float4*)Wop)[(size_t)n * 32 + ks * 8 + q];
            Bs[(q * 4 + 0) * 132 + n] = w.x;
            Bs[(q * 4 + 1) * 132 + n] = w.y;
            Bs[(q * 4 + 2) * 132 + n] = w.z;
            Bs[(q * 4 + 3) * 132 + n] = w.w;
        }
        __syncthreads();
#pragma unroll 4
        for (int k4 = 0; k4 < 8; k4++) {
            float4 a[4];
#pragma unroll
            for (int m = 0; m < 4; m++)
                a[m] = *(const float4*)&As[(tm * 4 + m) * 132 + ks * 32 + k4 * 4];
#pragma unroll
            for (int kk = 0; kk < 4; kk++) {
                float4 b = *(const float4*)&Bs[(k4 * 4 + kk) * 132 + tn * 4];
#pragma unroll
                for (int m = 0; m < 4; m++) {
                    float av = ((const float*)&a[m])[kk];
                    acc[m][0] += av * b.x; acc[m][1] += av * b.y;
                    acc[m][2] += av * b.z; acc[m][3] += av * b.w;
                }
            }
        }
    }

#pragma unroll
    for (int m = 0; m < 4; m++) {
        int row = m0 + tm * 4 + m;
        if (row < M) {
            float4* o = (float4*)&out[(size_t)row * C + tn * 4];
            float4 r = *o;                   // residual self_feat
            r.x += acc[m][0] + bopS[tn * 4 + 0];
            r.y += acc[m][1] + bopS[tn * 4 + 1];
            r.z += acc[m][2] + bopS[tn * 4 + 2];
            r.w += acc[m][3] + bopS[tn * 4 + 3];
            *o = r;
        }
    }
}

// ---------------------------------------------------------------------------
extern "C" void kernel_launch(void* const* d_in, const int* in_sizes, int n_in,
                              void* d_out, int out_size, void* d_ws, size_t ws_size,
                              hipStream_t stream) {
    const float* x_user = (const float*)d_in[0];
    const float* x_item = (const float*)d_in[1];
    const int*   ei_u2i = (const int*)d_in[2];
    const int*   ei_i2u = (const int*)d_in[3];
    const float* W_nb   = (const float*)d_in[4];
    const float* b_nb   = (const float*)d_in[5];
    const float* W_self = (const float*)d_in[6];
    const float* b_self = (const float*)d_in[7];
    const float* Wip    = (const float*)d_in[8];
    const float* bip    = (const float*)d_in[9];
    const float* Wop    = (const float*)d_in[10];
    const float* bop    = (const float*)d_in[11];

    const int NU = in_sizes[0] / C;
    const int NI = in_sizes[1] / C;
    const int E1 = in_sizes[2] / 2;
    const int E2 = in_sizes[3] / 2;

    float* out_user = (float*)d_out;
    float* out_item = out_user + (size_t)NU * C;

    // workspace layout: h (rc) | omean (rc) | cur (maxN ints) | csr (maxE ints)
    float* ws = (float*)d_ws;
    const size_t rc = (size_t)(NU + NI) * C;
    float* h_all     = ws;
    float* omean_all = h_all + rc;
    int*   cur       = (int*)(omean_all + rc);
    const int maxN   = (NU > NI) ? NU : NI;
    int*   csr       = cur + maxN;

    float* h_user = h_all;
    float* h_item = h_all + (size_t)NU * C;
    float* om_user = omean_all;
    float* om_item = omean_all + (size_t)NU * C;

    // transforms (self feat -> d_out, neighbor feat -> h)
    transform_kernel<<<(NU + 31) / 32, 256, 0, stream>>>(
        x_user, NU, W_nb, b_nb, W_self, b_self, h_user, out_user);
    transform_kernel<<<(NI + 31) / 32, 256, 0, stream>>>(
        x_item, NI, W_nb, b_nb, W_self, b_self, h_item, out_item);

    // direction A: user -> item  (dst = items)
    zero_kernel<<<(NI + 255) / 256, 256, 0, stream>>>(cur, NI);
    hist_kernel<<<(E1 + 255) / 256, 256, 0, stream>>>(ei_u2i + E1, E1, cur);
    scan_kernel<<<1, 1024, 0, stream>>>(cur, NI);
    fill_kernel<<<(E1 + 255) / 256, 256, 0, stream>>>(ei_u2i, ei_u2i + E1, E1, cur, csr);
    attn_fused_kernel<<<(NI + ATN - 1) / ATN, 256, 0, stream>>>(
        h_user, csr, cur, out_item, Wip, bip, om_item, NI);

    // direction B: item -> user  (dst = users)
    zero_kernel<<<(NU + 255) / 256, 256, 0, stream>>>(cur, NU);
    hist_kernel<<<(E2 + 255) / 256, 256, 0, stream>>>(ei_i2u + E2, E2, cur);
    scan_kernel<<<1, 1024, 0, stream>>>(cur, NU);
    fill_kernel<<<(E2 + 255) / 256, 256, 0, stream>>>(ei_i2u, ei_i2u + E2, E2, cur, csr);
    attn_fused_kernel<<<(NU + ATN - 1) / ATN, 256, 0, stream>>>(
        h_item, csr, cur, out_user, Wip, bip, om_user, NU);

    // out = self + omean @ Wop^T + bop (both types in one launch)
    outproj_kernel<<<(NU + NI + 31) / 32, 256, 0, stream>>>(
        omean_all, Wop, bop, (float*)d_out, NU + NI);
}